// Round 21
// baseline (135.538 us; speedup 1.0000x reference)
//
#include <hip/hip_runtime.h>

#define HW 3136
#define NB 32
#define NC 128
#define XST 132          // Xc/W row stride (floats), 16B-aligned rows
#define SST 36           // S/Sinv row stride
#define LAMV 0.01001f    // REG_DIAG + REG_EPS
// Row permutation: even rows -> slots 0..15, odd rows -> slots 16..31.
#define SIG(r) (((((r) & 1)) << 4) | ((r) >> 1))

// VOP3P v_pk_fma_f32 helpers (proven R10-R20).
static __device__ __forceinline__ float2 pka0(float2 c, float2 v, float2 a) {
  float2 d;
  asm("v_pk_fma_f32 %0, %1, %2, %3 op_sel:[0,0,0] op_sel_hi:[0,1,1]"
      : "=v"(d) : "v"(c), "v"(v), "v"(a));
  return d;
}
static __device__ __forceinline__ float2 pka1(float2 c, float2 v, float2 a) {
  float2 d;
  asm("v_pk_fma_f32 %0, %1, %2, %3 op_sel:[1,0,0] op_sel_hi:[1,1,1]"
      : "=v"(d) : "v"(c), "v"(v), "v"(a));
  return d;
}
static __device__ __forceinline__ float2 pke(float2 a, float2 b, float2 c) {
  float2 d;
  asm("v_pk_fma_f32 %0, %1, %2, %3"
      : "=v"(d) : "v"(a), "v"(b), "v"(c));
  return d;
}

__global__ __launch_bounds__(512, 8)
void mvg_kernel(const float* __restrict__ emb, float* __restrict__ out) {
  // XCD-bijective swizzle (3136 = 8*392): contiguous pos chunk per XCD.
  const int bid = blockIdx.x;
  const int pos = (bid & 7) * 392 + (bid >> 3);
  const int t = threadIdx.x;

  __shared__ __align__(16) float XcB[NB * XST];   // sigma-permuted rows
  __shared__ __align__(16) float WB[NB * XST];    // sigma-permuted rows
  __shared__ __align__(16) float SB[32 * SST];    // sigma-permuted rows
  __shared__ __align__(16) float ms[NC];

  // ---- gather (B, C) slice into permuted slots ----
  #pragma unroll
  for (int m = 0; m < 8; ++m) {
    const int idx = t + 512 * m;
    const int b = idx >> 7;
    const int c = idx & (NC - 1);
    XcB[SIG(b) * XST + c] = emb[(size_t)b * (size_t)(NC * HW) + (size_t)c * HW + pos];
  }
  __syncthreads();

  // ---- mean (slot-order sum == row-order sum), write mean output ----
  if (t < NC) {
    float s = 0.f;
    #pragma unroll
    for (int b = 0; b < NB; ++b) s += XcB[b * XST + t];
    const float m = s * (1.0f / NB);
    ms[t] = m;
    out[(size_t)t * HW + pos] = m;
  }
  __syncthreads();

  // ---- center ----
  #pragma unroll
  for (int m = 0; m < 8; ++m) {
    const int idx = t + 512 * m;
    const int b = idx >> 7;
    const int c = idx & (NC - 1);
    XcB[b * XST + c] -= ms[c];
  }
  __syncthreads();

  // ---- P1: S = lam*I + Xc Xc^T / 31 — symmetric 2x2 tiles, K-SPLIT x2:
  //      pair (2L, 2L+1) each does half of K (64), combined via shfl_xor.
  //      272 threads -> ~4.25 active waves (vs 2.1) to hide DS latency.
  //      Pair bank collision is 2-way only (free per m136). ----
  if (t < 272) {
    const int L = t >> 1;
    const int h = t & 1;
    const float fs = sqrtf(1089.0f - 8.0f * (float)L);
    const int I = (int)floorf((33.0f - fs) * 0.5f);
    const int J = I + L - (I * (33 - I)) / 2;
    const float* xi0 = &XcB[I * XST];           // row 2I
    const float* xi1 = &XcB[(16 + I) * XST];    // row 2I+1
    const float* xj0 = &XcB[J * XST];           // row 2J
    const float* xj1 = &XcB[(16 + J) * XST];    // row 2J+1
    const int cbase = h << 6;                   // half-K range [cbase, cbase+64)
    float2 d00 = make_float2(0.f, 0.f), d01 = make_float2(0.f, 0.f);
    float2 d10 = make_float2(0.f, 0.f), d11 = make_float2(0.f, 0.f);
    #pragma unroll 8
    for (int cc = 0; cc < 64; cc += 4) {
      const int c = cbase + cc;
      const float4 a0 = *(const float4*)&xi0[c];
      const float4 a1 = *(const float4*)&xi1[c];
      const float4 b0 = *(const float4*)&xj0[c];
      const float4 b1 = *(const float4*)&xj1[c];
      const float2 a0L = make_float2(a0.x, a0.y), a0H = make_float2(a0.z, a0.w);
      const float2 a1L = make_float2(a1.x, a1.y), a1H = make_float2(a1.z, a1.w);
      const float2 b0L = make_float2(b0.x, b0.y), b0H = make_float2(b0.z, b0.w);
      const float2 b1L = make_float2(b1.x, b1.y), b1H = make_float2(b1.z, b1.w);
      d00 = pke(a0L, b0L, d00); d00 = pke(a0H, b0H, d00);
      d01 = pke(a0L, b1L, d01); d01 = pke(a0H, b1H, d01);
      d10 = pke(a1L, b0L, d10); d10 = pke(a1H, b0H, d10);
      d11 = pke(a1L, b1L, d11); d11 = pke(a1H, b1H, d11);
    }
    float s00 = d00.x + d00.y;
    float s01 = d01.x + d01.y;
    float s10 = d10.x + d10.y;
    float s11 = d11.x + d11.y;
    s00 += __shfl_xor(s00, 1);
    s01 += __shfl_xor(s01, 1);
    s10 += __shfl_xor(s10, 1);
    s11 += __shfl_xor(s11, 1);
    if (h == 0) {
      const float s31 = 1.0f / 31.0f;
      const float dg = (I == J) ? LAMV : 0.f;
      float2 e0, e1;
      e0.x = s00 * s31 + dg;                    // (2I,   2J)
      e0.y = s01 * s31;                         // (2I,   2J+1)
      e1.x = s10 * s31;                         // (2I+1, 2J)
      e1.y = s11 * s31 + dg;                    // (2I+1, 2J+1)
      *(float2*)&SB[I * SST + 2 * J] = e0;
      *(float2*)&SB[(16 + I) * SST + 2 * J] = e1;
      if (I != J) {                             // mirror (transpose in regs)
        *(float2*)&SB[J * SST + 2 * I] = make_float2(e0.x, e1.x);
        *(float2*)&SB[(16 + J) * SST + 2 * I] = make_float2(e0.y, e1.y);
      }
    }
  }
  __syncthreads();

  // ---- P2: wave 0 sweeps S (32 pivots) with SHUFFLE-ONLY broadcasts
  //      (proven R15-R20; LDS-broadcast variants spill or race). ----
  if (t < 64) {
    const int r = t & 31;
    const int hb = (t >> 5) << 4;
    const int rs = SIG(r);                      // storage slot of row r
    float m[16];
    #pragma unroll
    for (int j = 0; j < 4; ++j) {
      const float4 v = *(const float4*)&SB[rs * SST + hb + 4 * j];
      m[4 * j] = v.x; m[4 * j + 1] = v.y; m[4 * j + 2] = v.z; m[4 * j + 3] = v.w;
    }

    #define SWEEP_K(K) {                                                    \
      float pc = m[(K) & 15] - ((r == (K)) ? 1.0f : 0.0f);                  \
      const float dm1 = __shfl(pc, (((K) >> 4) << 5) + (K), 64);            \
      const float cr  = __shfl(pc, (((K) >> 4) << 5) + r, 64);              \
      const float g = cr * __builtin_amdgcn_rcpf(dm1 + 1.0f);               \
      float hj[16];                                                         \
      _Pragma("unroll")                                                     \
      for (int j = 0; j < 16; ++j)                                          \
        hj[j] = __shfl(pc, (((K) >> 4) << 5) + hb + j, 64);                 \
      _Pragma("unroll")                                                     \
      for (int j = 0; j < 16; ++j) m[j] = fmaf(-g, hj[j], m[j]);            \
    }

    SWEEP_K(0)  SWEEP_K(1)  SWEEP_K(2)  SWEEP_K(3)
    SWEEP_K(4)  SWEEP_K(5)  SWEEP_K(6)  SWEEP_K(7)
    SWEEP_K(8)  SWEEP_K(9)  SWEEP_K(10) SWEEP_K(11)
    SWEEP_K(12) SWEEP_K(13) SWEEP_K(14) SWEEP_K(15)
    SWEEP_K(16) SWEEP_K(17) SWEEP_K(18) SWEEP_K(19)
    SWEEP_K(20) SWEEP_K(21) SWEEP_K(22) SWEEP_K(23)
    SWEEP_K(24) SWEEP_K(25) SWEEP_K(26) SWEEP_K(27)
    SWEEP_K(28) SWEEP_K(29) SWEEP_K(30) SWEEP_K(31)

    // Sinv = -(swept), diag = 2 - (swept)
    #pragma unroll
    for (int j = 0; j < 16; ++j) {
      const int col = hb + j;
      SB[rs * SST + col] = (col == r) ? (2.0f - m[j]) : (-m[j]);
    }
  }
  __syncthreads();

  // ---- P3: W = Sinv * Xc; thread owns rows (2s2, 2s2+1) x split cols
  //      {CA..CA+3, CB..CB+3}, CA = 4*(t&15), CB = 64+CA (2-way, free). ----
  if (t < 256) {
    const int s2 = t >> 4;
    const int CA = (t & 15) << 2;
    const int CB = 64 + CA;
    float2 w0[4], w1[4];
    #pragma unroll
    for (int q = 0; q < 4; ++q) {
      w0[q] = make_float2(0.f, 0.f);
      w1[q] = make_float2(0.f, 0.f);
    }
    #pragma unroll 2
    for (int j = 0; j < 32; j += 4) {
      const float4 sv0 = *(const float4*)&SB[s2 * SST + j];         // row 2s2
      const float4 sv1 = *(const float4*)&SB[(16 + s2) * SST + j];  // row 2s2+1
      const float2 s0L = make_float2(sv0.x, sv0.y), s0H = make_float2(sv0.z, sv0.w);
      const float2 s1L = make_float2(sv1.x, sv1.y), s1H = make_float2(sv1.z, sv1.w);
      const int jh = j >> 1;
      const float* xr0 = &XcB[jh * XST];            // row j
      const float* xr1 = &XcB[(16 + jh) * XST];     // row j+1
      const float* xr2 = &XcB[(jh + 1) * XST];      // row j+2
      const float* xr3 = &XcB[(17 + jh) * XST];     // row j+3
      {
        const float4 a = *(const float4*)&xr0[CA];
        const float4 b = *(const float4*)&xr0[CB];
        w0[0] = pka0(s0L, make_float2(a.x, a.y), w0[0]);
        w0[1] = pka0(s0L, make_float2(a.z, a.w), w0[1]);
        w0[2] = pka0(s0L, make_float2(b.x, b.y), w0[2]);
        w0[3] = pka0(s0L, make_float2(b.z, b.w), w0[3]);
        w1[0] = pka0(s1L, make_float2(a.x, a.y), w1[0]);
        w1[1] = pka0(s1L, make_float2(a.z, a.w), w1[1]);
        w1[2] = pka0(s1L, make_float2(b.x, b.y), w1[2]);
        w1[3] = pka0(s1L, make_float2(b.z, b.w), w1[3]);
      }
      {
        const float4 a = *(const float4*)&xr1[CA];
        const float4 b = *(const float4*)&xr1[CB];
        w0[0] = pka1(s0L, make_float2(a.x, a.y), w0[0]);
        w0[1] = pka1(s0L, make_float2(a.z, a.w), w0[1]);
        w0[2] = pka1(s0L, make_float2(b.x, b.y), w0[2]);
        w0[3] = pka1(s0L, make_float2(b.z, b.w), w0[3]);
        w1[0] = pka1(s1L, make_float2(a.x, a.y), w1[0]);
        w1[1] = pka1(s1L, make_float2(a.z, a.w), w1[1]);
        w1[2] = pka1(s1L, make_float2(b.x, b.y), w1[2]);
        w1[3] = pka1(s1L, make_float2(b.z, b.w), w1[3]);
      }
      {
        const float4 a = *(const float4*)&xr2[CA];
        const float4 b = *(const float4*)&xr2[CB];
        w0[0] = pka0(s0H, make_float2(a.x, a.y), w0[0]);
        w0[1] = pka0(s0H, make_float2(a.z, a.w), w0[1]);
        w0[2] = pka0(s0H, make_float2(b.x, b.y), w0[2]);
        w0[3] = pka0(s0H, make_float2(b.z, b.w), w0[3]);
        w1[0] = pka0(s1H, make_float2(a.x, a.y), w1[0]);
        w1[1] = pka0(s1H, make_float2(a.z, a.w), w1[1]);
        w1[2] = pka0(s1H, make_float2(b.x, b.y), w1[2]);
        w1[3] = pka0(s1H, make_float2(b.z, b.w), w1[3]);
      }
      {
        const float4 a = *(const float4*)&xr3[CA];
        const float4 b = *(const float4*)&xr3[CB];
        w0[0] = pka1(s0H, make_float2(a.x, a.y), w0[0]);
        w0[1] = pka1(s0H, make_float2(a.z, a.w), w0[1]);
        w0[2] = pka1(s0H, make_float2(b.x, b.y), w0[2]);
        w0[3] = pka1(s0H, make_float2(b.z, b.w), w0[3]);
        w1[0] = pka1(s1H, make_float2(a.x, a.y), w1[0]);
        w1[1] = pka1(s1H, make_float2(a.z, a.w), w1[1]);
        w1[2] = pka1(s1H, make_float2(b.x, b.y), w1[2]);
        w1[3] = pka1(s1H, make_float2(b.z, b.w), w1[3]);
      }
    }
    *(float4*)&WB[s2 * XST + CA] = make_float4(w0[0].x, w0[0].y, w0[1].x, w0[1].y);
    *(float4*)&WB[s2 * XST + CB] = make_float4(w0[2].x, w0[2].y, w0[3].x, w0[3].y);
    *(float4*)&WB[(16 + s2) * XST + CA] = make_float4(w1[0].x, w1[0].y, w1[1].x, w1[1].y);
    *(float4*)&WB[(16 + s2) * XST + CB] = make_float4(w1[2].x, w1[2].y, w1[3].x, w1[3].y);
  }
  __syncthreads();

  // ---- P4: P = Xc^T W, symmetric (136 diag+upper 8x8 tiles, 2 threads
  //      per tile), mirror stores for the lower triangle. ----
  if (t < 272) {
    const int L = t >> 1;
    const int half = t & 1;
    const float fs = sqrtf(1089.0f - 8.0f * (float)L);
    const int R = (int)floorf((33.0f - fs) * 0.5f);
    const int C = R + L - (R * (33 - R)) / 2;
    const int r8 = R << 3;
    const int cb = (C << 3) + (half << 2);

    float2 aP[8][2];
    #pragma unroll
    for (int r = 0; r < 8; ++r) {
      aP[r][0] = make_float2(0.f, 0.f);
      aP[r][1] = make_float2(0.f, 0.f);
    }
    #pragma unroll 4
    for (int u = 0; u < 32; ++u) {
      const float4 cv0 = *(const float4*)&XcB[u * XST + r8];
      const float4 cv1 = *(const float4*)&XcB[u * XST + r8 + 4];
      const float4 rv  = *(const float4*)&WB[u * XST + cb];
      const float2 rL = make_float2(rv.x, rv.y), rH = make_float2(rv.z, rv.w);
      const float2 c01 = make_float2(cv0.x, cv0.y), c23 = make_float2(cv0.z, cv0.w);
      const float2 c45 = make_float2(cv1.x, cv1.y), c67 = make_float2(cv1.z, cv1.w);
      aP[0][0] = pka0(c01, rL, aP[0][0]); aP[0][1] = pka0(c01, rH, aP[0][1]);
      aP[1][0] = pka1(c01, rL, aP[1][0]); aP[1][1] = pka1(c01, rH, aP[1][1]);
      aP[2][0] = pka0(c23, rL, aP[2][0]); aP[2][1] = pka0(c23, rH, aP[2][1]);
      aP[3][0] = pka1(c23, rL, aP[3][0]); aP[3][1] = pka1(c23, rH, aP[3][1]);
      aP[4][0] = pka0(c45, rL, aP[4][0]); aP[4][1] = pka0(c45, rH, aP[4][1]);
      aP[5][0] = pka1(c45, rL, aP[5][0]); aP[5][1] = pka1(c45, rH, aP[5][1]);
      aP[6][0] = pka0(c67, rL, aP[6][0]); aP[6][1] = pka0(c67, rH, aP[6][1]);
      aP[7][0] = pka1(c67, rL, aP[7][0]); aP[7][1] = pka1(c67, rH, aP[7][1]);
    }

    const float ILAM = 1.0f / LAMV;
    const float IL31 = ILAM / 31.0f;
    float* o = out + (size_t)NC * HW + (size_t)pos * (NC * NC);

    // direct store (upper/diag): rows r8..r8+7, cols cb..cb+3
    #pragma unroll
    for (int r = 0; r < 8; ++r) {
      const int gr = r8 + r;
      float4 w;
      w.x = fmaf(-IL31, aP[r][0].x, (gr == cb + 0) ? ILAM : 0.f);
      w.y = fmaf(-IL31, aP[r][0].y, (gr == cb + 1) ? ILAM : 0.f);
      w.z = fmaf(-IL31, aP[r][1].x, (gr == cb + 2) ? ILAM : 0.f);
      w.w = fmaf(-IL31, aP[r][1].y, (gr == cb + 3) ? ILAM : 0.f);
      *(float4*)&o[(size_t)gr * NC + cb] = w;
    }

    // mirror store (strict lower): rows cb..cb+3, cols r8..r8+7
    if (R != C) {
      {
        const float4 m0 = make_float4(-IL31 * aP[0][0].x, -IL31 * aP[1][0].x,
                                      -IL31 * aP[2][0].x, -IL31 * aP[3][0].x);
        const float4 m1 = make_float4(-IL31 * aP[4][0].x, -IL31 * aP[5][0].x,
                                      -IL31 * aP[6][0].x, -IL31 * aP[7][0].x);
        *(float4*)&o[(size_t)(cb + 0) * NC + r8] = m0;
        *(float4*)&o[(size_t)(cb + 0) * NC + r8 + 4] = m1;
      }
      {
        const float4 m0 = make_float4(-IL31 * aP[0][0].y, -IL31 * aP[1][0].y,
                                      -IL31 * aP[2][0].y, -IL31 * aP[3][0].y);
        const float4 m1 = make_float4(-IL31 * aP[4][0].y, -IL31 * aP[5][0].y,
                                      -IL31 * aP[6][0].y, -IL31 * aP[7][0].y);
        *(float4*)&o[(size_t)(cb + 1) * NC + r8] = m0;
        *(float4*)&o[(size_t)(cb + 1) * NC + r8 + 4] = m1;
      }
      {
        const float4 m0 = make_float4(-IL31 * aP[0][1].x, -IL31 * aP[1][1].x,
                                      -IL31 * aP[2][1].x, -IL31 * aP[3][1].x);
        const float4 m1 = make_float4(-IL31 * aP[4][1].x, -IL31 * aP[5][1].x,
                                      -IL31 * aP[6][1].x, -IL31 * aP[7][1].x);
        *(float4*)&o[(size_t)(cb + 2) * NC + r8] = m0;
        *(float4*)&o[(size_t)(cb + 2) * NC + r8 + 4] = m1;
      }
      {
        const float4 m0 = make_float4(-IL31 * aP[0][1].y, -IL31 * aP[1][1].y,
                                      -IL31 * aP[2][1].y, -IL31 * aP[3][1].y);
        const float4 m1 = make_float4(-IL31 * aP[4][1].y, -IL31 * aP[5][1].y,
                                      -IL31 * aP[6][1].y, -IL31 * aP[7][1].y);
        *(float4*)&o[(size_t)(cb + 3) * NC + r8] = m0;
        *(float4*)&o[(size_t)(cb + 3) * NC + r8 + 4] = m1;
      }
    }
  }
}

extern "C" void kernel_launch(void* const* d_in, const int* in_sizes, int n_in,
                              void* d_out, int out_size, void* d_ws, size_t ws_size,
                              hipStream_t stream) {
  const float* emb = (const float*)d_in[0];
  float* out = (float*)d_out;
  mvg_kernel<<<HW, 512, 0, stream>>>(emb, out);
}

// Round 22
// 130.096 us; speedup vs baseline: 1.0418x; 1.0418x over previous
//
#include <hip/hip_runtime.h>

#define HW 3136
#define NB 32
#define NC 128
#define XST 132          // Xc/W row stride (floats), 16B-aligned rows
#define SST 36           // S/Sinv row stride
#define LAMV 0.01001f    // REG_DIAG + REG_EPS
// Row permutation: even rows -> slots 0..15, odd rows -> slots 16..31.
#define SIG(r) (((((r) & 1)) << 4) | ((r) >> 1))

// VOP3P v_pk_fma_f32 helpers (proven R10-R20).
static __device__ __forceinline__ float2 pka0(float2 c, float2 v, float2 a) {
  float2 d;
  asm("v_pk_fma_f32 %0, %1, %2, %3 op_sel:[0,0,0] op_sel_hi:[0,1,1]"
      : "=v"(d) : "v"(c), "v"(v), "v"(a));
  return d;
}
static __device__ __forceinline__ float2 pka1(float2 c, float2 v, float2 a) {
  float2 d;
  asm("v_pk_fma_f32 %0, %1, %2, %3 op_sel:[1,0,0] op_sel_hi:[1,1,1]"
      : "=v"(d) : "v"(c), "v"(v), "v"(a));
  return d;
}
static __device__ __forceinline__ float2 pke(float2 a, float2 b, float2 c) {
  float2 d;
  asm("v_pk_fma_f32 %0, %1, %2, %3"
      : "=v"(d) : "v"(a), "v"(b), "v"(c));
  return d;
}

__global__ __launch_bounds__(512, 8)
void mvg_kernel(const float* __restrict__ emb, float* __restrict__ out) {
  // XCD-bijective swizzle (3136 = 8*392): contiguous pos chunk per XCD.
  const int bid = blockIdx.x;
  const int pos = (bid & 7) * 392 + (bid >> 3);
  const int t = threadIdx.x;

  __shared__ __align__(16) float XcB[NB * XST];   // sigma-permuted rows
  __shared__ __align__(16) float WB[NB * XST];    // sigma-permuted rows
  __shared__ __align__(16) float SB[32 * SST];    // sigma-permuted rows
  __shared__ __align__(16) float ms[NC];

  // ---- gather (B, C) slice into permuted slots ----
  #pragma unroll
  for (int m = 0; m < 8; ++m) {
    const int idx = t + 512 * m;
    const int b = idx >> 7;
    const int c = idx & (NC - 1);
    XcB[SIG(b) * XST + c] = emb[(size_t)b * (size_t)(NC * HW) + (size_t)c * HW + pos];
  }
  __syncthreads();

  // ---- mean (slot-order sum == row-order sum), write mean output ----
  if (t < NC) {
    float s = 0.f;
    #pragma unroll
    for (int b = 0; b < NB; ++b) s += XcB[b * XST + t];
    const float m = s * (1.0f / NB);
    ms[t] = m;
    out[(size_t)t * HW + pos] = m;
  }
  __syncthreads();

  // ---- center ----
  #pragma unroll
  for (int m = 0; m < 8; ++m) {
    const int idx = t + 512 * m;
    const int b = idx >> 7;
    const int c = idx & (NC - 1);
    XcB[b * XST + c] -= ms[c];
  }
  __syncthreads();

  // ---- P1: S = lam*I + Xc Xc^T / 31 — SYMMETRIC: 136 upper 2x2 tiles ----
  if (t < 136) {
    const float fs = sqrtf(1089.0f - 8.0f * (float)t);
    const int I = (int)floorf((33.0f - fs) * 0.5f);
    const int J = I + t - (I * (33 - I)) / 2;
    const float* xi0 = &XcB[I * XST];           // row 2I
    const float* xi1 = &XcB[(16 + I) * XST];    // row 2I+1
    const float* xj0 = &XcB[J * XST];           // row 2J
    const float* xj1 = &XcB[(16 + J) * XST];    // row 2J+1
    float2 d00 = make_float2(0.f, 0.f), d01 = make_float2(0.f, 0.f);
    float2 d10 = make_float2(0.f, 0.f), d11 = make_float2(0.f, 0.f);
    #pragma unroll 8
    for (int c = 0; c < NC; c += 4) {
      const float4 a0 = *(const float4*)&xi0[c];
      const float4 a1 = *(const float4*)&xi1[c];
      const float4 b0 = *(const float4*)&xj0[c];
      const float4 b1 = *(const float4*)&xj1[c];
      const float2 a0L = make_float2(a0.x, a0.y), a0H = make_float2(a0.z, a0.w);
      const float2 a1L = make_float2(a1.x, a1.y), a1H = make_float2(a1.z, a1.w);
      const float2 b0L = make_float2(b0.x, b0.y), b0H = make_float2(b0.z, b0.w);
      const float2 b1L = make_float2(b1.x, b1.y), b1H = make_float2(b1.z, b1.w);
      d00 = pke(a0L, b0L, d00); d00 = pke(a0H, b0H, d00);
      d01 = pke(a0L, b1L, d01); d01 = pke(a0H, b1H, d01);
      d10 = pke(a1L, b0L, d10); d10 = pke(a1H, b0H, d10);
      d11 = pke(a1L, b1L, d11); d11 = pke(a1H, b1H, d11);
    }
    const float s31 = 1.0f / 31.0f;
    const float dg = (I == J) ? LAMV : 0.f;
    float2 e0, e1;
    e0.x = (d00.x + d00.y) * s31 + dg;          // (2I,   2J)
    e0.y = (d01.x + d01.y) * s31;               // (2I,   2J+1)
    e1.x = (d10.x + d10.y) * s31;               // (2I+1, 2J)
    e1.y = (d11.x + d11.y) * s31 + dg;          // (2I+1, 2J+1)
    *(float2*)&SB[I * SST + 2 * J] = e0;
    *(float2*)&SB[(16 + I) * SST + 2 * J] = e1;
    if (I != J) {                               // mirror (transpose in regs)
      *(float2*)&SB[J * SST + 2 * I] = make_float2(e0.x, e1.x);
      *(float2*)&SB[(16 + J) * SST + 2 * I] = make_float2(e0.y, e1.y);
    }
  }
  __syncthreads();

  // ---- P2: wave 0 sweeps S (32 pivots) with SHUFFLE-ONLY broadcasts
  //      (proven R15-R20; LDS-broadcast variants spill or race). ----
  if (t < 64) {
    const int r = t & 31;
    const int hb = (t >> 5) << 4;
    const int rs = SIG(r);                      // storage slot of row r
    float m[16];
    #pragma unroll
    for (int j = 0; j < 4; ++j) {
      const float4 v = *(const float4*)&SB[rs * SST + hb + 4 * j];
      m[4 * j] = v.x; m[4 * j + 1] = v.y; m[4 * j + 2] = v.z; m[4 * j + 3] = v.w;
    }

    #define SWEEP_K(K) {                                                    \
      float pc = m[(K) & 15] - ((r == (K)) ? 1.0f : 0.0f);                  \
      const float dm1 = __shfl(pc, (((K) >> 4) << 5) + (K), 64);            \
      const float cr  = __shfl(pc, (((K) >> 4) << 5) + r, 64);              \
      const float g = cr * __builtin_amdgcn_rcpf(dm1 + 1.0f);               \
      float hj[16];                                                         \
      _Pragma("unroll")                                                     \
      for (int j = 0; j < 16; ++j)                                          \
        hj[j] = __shfl(pc, (((K) >> 4) << 5) + hb + j, 64);                 \
      _Pragma("unroll")                                                     \
      for (int j = 0; j < 16; ++j) m[j] = fmaf(-g, hj[j], m[j]);            \
    }

    SWEEP_K(0)  SWEEP_K(1)  SWEEP_K(2)  SWEEP_K(3)
    SWEEP_K(4)  SWEEP_K(5)  SWEEP_K(6)  SWEEP_K(7)
    SWEEP_K(8)  SWEEP_K(9)  SWEEP_K(10) SWEEP_K(11)
    SWEEP_K(12) SWEEP_K(13) SWEEP_K(14) SWEEP_K(15)
    SWEEP_K(16) SWEEP_K(17) SWEEP_K(18) SWEEP_K(19)
    SWEEP_K(20) SWEEP_K(21) SWEEP_K(22) SWEEP_K(23)
    SWEEP_K(24) SWEEP_K(25) SWEEP_K(26) SWEEP_K(27)
    SWEEP_K(28) SWEEP_K(29) SWEEP_K(30) SWEEP_K(31)

    // Sinv = -(swept), diag = 2 - (swept)
    #pragma unroll
    for (int j = 0; j < 16; ++j) {
      const int col = hb + j;
      SB[rs * SST + col] = (col == r) ? (2.0f - m[j]) : (-m[j]);
    }
  }
  __syncthreads();

  // ---- P3: W = Sinv * Xc; thread owns rows (2s2, 2s2+1) x split cols
  //      {CA..CA+3, CB..CB+3}, CA = 4*(t&15), CB = 64+CA (2-way, free). ----
  if (t < 256) {
    const int s2 = t >> 4;
    const int CA = (t & 15) << 2;
    const int CB = 64 + CA;
    float2 w0[4], w1[4];
    #pragma unroll
    for (int q = 0; q < 4; ++q) {
      w0[q] = make_float2(0.f, 0.f);
      w1[q] = make_float2(0.f, 0.f);
    }
    #pragma unroll 2
    for (int j = 0; j < 32; j += 4) {
      const float4 sv0 = *(const float4*)&SB[s2 * SST + j];         // row 2s2
      const float4 sv1 = *(const float4*)&SB[(16 + s2) * SST + j];  // row 2s2+1
      const float2 s0L = make_float2(sv0.x, sv0.y), s0H = make_float2(sv0.z, sv0.w);
      const float2 s1L = make_float2(sv1.x, sv1.y), s1H = make_float2(sv1.z, sv1.w);
      const int jh = j >> 1;
      const float* xr0 = &XcB[jh * XST];            // row j
      const float* xr1 = &XcB[(16 + jh) * XST];     // row j+1
      const float* xr2 = &XcB[(jh + 1) * XST];      // row j+2
      const float* xr3 = &XcB[(17 + jh) * XST];     // row j+3
      {
        const float4 a = *(const float4*)&xr0[CA];
        const float4 b = *(const float4*)&xr0[CB];
        w0[0] = pka0(s0L, make_float2(a.x, a.y), w0[0]);
        w0[1] = pka0(s0L, make_float2(a.z, a.w), w0[1]);
        w0[2] = pka0(s0L, make_float2(b.x, b.y), w0[2]);
        w0[3] = pka0(s0L, make_float2(b.z, b.w), w0[3]);
        w1[0] = pka0(s1L, make_float2(a.x, a.y), w1[0]);
        w1[1] = pka0(s1L, make_float2(a.z, a.w), w1[1]);
        w1[2] = pka0(s1L, make_float2(b.x, b.y), w1[2]);
        w1[3] = pka0(s1L, make_float2(b.z, b.w), w1[3]);
      }
      {
        const float4 a = *(const float4*)&xr1[CA];
        const float4 b = *(const float4*)&xr1[CB];
        w0[0] = pka1(s0L, make_float2(a.x, a.y), w0[0]);
        w0[1] = pka1(s0L, make_float2(a.z, a.w), w0[1]);
        w0[2] = pka1(s0L, make_float2(b.x, b.y), w0[2]);
        w0[3] = pka1(s0L, make_float2(b.z, b.w), w0[3]);
        w1[0] = pka1(s1L, make_float2(a.x, a.y), w1[0]);
        w1[1] = pka1(s1L, make_float2(a.z, a.w), w1[1]);
        w1[2] = pka1(s1L, make_float2(b.x, b.y), w1[2]);
        w1[3] = pka1(s1L, make_float2(b.z, b.w), w1[3]);
      }
      {
        const float4 a = *(const float4*)&xr2[CA];
        const float4 b = *(const float4*)&xr2[CB];
        w0[0] = pka0(s0H, make_float2(a.x, a.y), w0[0]);
        w0[1] = pka0(s0H, make_float2(a.z, a.w), w0[1]);
        w0[2] = pka0(s0H, make_float2(b.x, b.y), w0[2]);
        w0[3] = pka0(s0H, make_float2(b.z, b.w), w0[3]);
        w1[0] = pka0(s1H, make_float2(a.x, a.y), w1[0]);
        w1[1] = pka0(s1H, make_float2(a.z, a.w), w1[1]);
        w1[2] = pka0(s1H, make_float2(b.x, b.y), w1[2]);
        w1[3] = pka0(s1H, make_float2(b.z, b.w), w1[3]);
      }
      {
        const float4 a = *(const float4*)&xr3[CA];
        const float4 b = *(const float4*)&xr3[CB];
        w0[0] = pka1(s0H, make_float2(a.x, a.y), w0[0]);
        w0[1] = pka1(s0H, make_float2(a.z, a.w), w0[1]);
        w0[2] = pka1(s0H, make_float2(b.x, b.y), w0[2]);
        w0[3] = pka1(s0H, make_float2(b.z, b.w), w0[3]);
        w1[0] = pka1(s1H, make_float2(a.x, a.y), w1[0]);
        w1[1] = pka1(s1H, make_float2(a.z, a.w), w1[1]);
        w1[2] = pka1(s1H, make_float2(b.x, b.y), w1[2]);
        w1[3] = pka1(s1H, make_float2(b.z, b.w), w1[3]);
      }
    }
    *(float4*)&WB[s2 * XST + CA] = make_float4(w0[0].x, w0[0].y, w0[1].x, w0[1].y);
    *(float4*)&WB[s2 * XST + CB] = make_float4(w0[2].x, w0[2].y, w0[3].x, w0[3].y);
    *(float4*)&WB[(16 + s2) * XST + CA] = make_float4(w1[0].x, w1[0].y, w1[1].x, w1[1].y);
    *(float4*)&WB[(16 + s2) * XST + CB] = make_float4(w1[2].x, w1[2].y, w1[3].x, w1[3].y);
  }
  __syncthreads();

  // ---- P4: P = Xc^T W, symmetric (136 diag+upper 8x8 tiles, 2 threads
  //      per tile), mirror stores for the lower triangle. ----
  if (t < 272) {
    const int L = t >> 1;
    const int half = t & 1;
    const float fs = sqrtf(1089.0f - 8.0f * (float)L);
    const int R = (int)floorf((33.0f - fs) * 0.5f);
    const int C = R + L - (R * (33 - R)) / 2;
    const int r8 = R << 3;
    const int cb = (C << 3) + (half << 2);

    float2 aP[8][2];
    #pragma unroll
    for (int r = 0; r < 8; ++r) {
      aP[r][0] = make_float2(0.f, 0.f);
      aP[r][1] = make_float2(0.f, 0.f);
    }
    #pragma unroll 4
    for (int u = 0; u < 32; ++u) {
      const float4 cv0 = *(const float4*)&XcB[u * XST + r8];
      const float4 cv1 = *(const float4*)&XcB[u * XST + r8 + 4];
      const float4 rv  = *(const float4*)&WB[u * XST + cb];
      const float2 rL = make_float2(rv.x, rv.y), rH = make_float2(rv.z, rv.w);
      const float2 c01 = make_float2(cv0.x, cv0.y), c23 = make_float2(cv0.z, cv0.w);
      const float2 c45 = make_float2(cv1.x, cv1.y), c67 = make_float2(cv1.z, cv1.w);
      aP[0][0] = pka0(c01, rL, aP[0][0]); aP[0][1] = pka0(c01, rH, aP[0][1]);
      aP[1][0] = pka1(c01, rL, aP[1][0]); aP[1][1] = pka1(c01, rH, aP[1][1]);
      aP[2][0] = pka0(c23, rL, aP[2][0]); aP[2][1] = pka0(c23, rH, aP[2][1]);
      aP[3][0] = pka1(c23, rL, aP[3][0]); aP[3][1] = pka1(c23, rH, aP[3][1]);
      aP[4][0] = pka0(c45, rL, aP[4][0]); aP[4][1] = pka0(c45, rH, aP[4][1]);
      aP[5][0] = pka1(c45, rL, aP[5][0]); aP[5][1] = pka1(c45, rH, aP[5][1]);
      aP[6][0] = pka0(c67, rL, aP[6][0]); aP[6][1] = pka0(c67, rH, aP[6][1]);
      aP[7][0] = pka1(c67, rL, aP[7][0]); aP[7][1] = pka1(c67, rH, aP[7][1]);
    }

    const float ILAM = 1.0f / LAMV;
    const float IL31 = ILAM / 31.0f;
    float* o = out + (size_t)NC * HW + (size_t)pos * (NC * NC);

    // direct store (upper/diag): rows r8..r8+7, cols cb..cb+3
    #pragma unroll
    for (int r = 0; r < 8; ++r) {
      const int gr = r8 + r;
      float4 w;
      w.x = fmaf(-IL31, aP[r][0].x, (gr == cb + 0) ? ILAM : 0.f);
      w.y = fmaf(-IL31, aP[r][0].y, (gr == cb + 1) ? ILAM : 0.f);
      w.z = fmaf(-IL31, aP[r][1].x, (gr == cb + 2) ? ILAM : 0.f);
      w.w = fmaf(-IL31, aP[r][1].y, (gr == cb + 3) ? ILAM : 0.f);
      *(float4*)&o[(size_t)gr * NC + cb] = w;
    }

    // mirror store (strict lower): rows cb..cb+3, cols r8..r8+7
    if (R != C) {
      {
        const float4 m0 = make_float4(-IL31 * aP[0][0].x, -IL31 * aP[1][0].x,
                                      -IL31 * aP[2][0].x, -IL31 * aP[3][0].x);
        const float4 m1 = make_float4(-IL31 * aP[4][0].x, -IL31 * aP[5][0].x,
                                      -IL31 * aP[6][0].x, -IL31 * aP[7][0].x);
        *(float4*)&o[(size_t)(cb + 0) * NC + r8] = m0;
        *(float4*)&o[(size_t)(cb + 0) * NC + r8 + 4] = m1;
      }
      {
        const float4 m0 = make_float4(-IL31 * aP[0][0].y, -IL31 * aP[1][0].y,
                                      -IL31 * aP[2][0].y, -IL31 * aP[3][0].y);
        const float4 m1 = make_float4(-IL31 * aP[4][0].y, -IL31 * aP[5][0].y,
                                      -IL31 * aP[6][0].y, -IL31 * aP[7][0].y);
        *(float4*)&o[(size_t)(cb + 1) * NC + r8] = m0;
        *(float4*)&o[(size_t)(cb + 1) * NC + r8 + 4] = m1;
      }
      {
        const float4 m0 = make_float4(-IL31 * aP[0][1].x, -IL31 * aP[1][1].x,
                                      -IL31 * aP[2][1].x, -IL31 * aP[3][1].x);
        const float4 m1 = make_float4(-IL31 * aP[4][1].x, -IL31 * aP[5][1].x,
                                      -IL31 * aP[6][1].x, -IL31 * aP[7][1].x);
        *(float4*)&o[(size_t)(cb + 2) * NC + r8] = m0;
        *(float4*)&o[(size_t)(cb + 2) * NC + r8 + 4] = m1;
      }
      {
        const float4 m0 = make_float4(-IL31 * aP[0][1].y, -IL31 * aP[1][1].y,
                                      -IL31 * aP[2][1].y, -IL31 * aP[3][1].y);
        const float4 m1 = make_float4(-IL31 * aP[4][1].y, -IL31 * aP[5][1].y,
                                      -IL31 * aP[6][1].y, -IL31 * aP[7][1].y);
        *(float4*)&o[(size_t)(cb + 3) * NC + r8] = m0;
        *(float4*)&o[(size_t)(cb + 3) * NC + r8 + 4] = m1;
      }
    }
  }
}

extern "C" void kernel_launch(void* const* d_in, const int* in_sizes, int n_in,
                              void* d_out, int out_size, void* d_ws, size_t ws_size,
                              hipStream_t stream) {
  const float* emb = (const float*)d_in[0];
  float* out = (float*)d_out;
  mvg_kernel<<<HW, 512, 0, stream>>>(emb, out);
}